// Round 9
// baseline (164.869 us; speedup 1.0000x reference)
//
#include <hip/hip_runtime.h>
#include <hip/hip_bf16.h>

typedef unsigned short ushort_t;
typedef __attribute__((ext_vector_type(8))) short v8s;   // 8 bf16 = 4 VGPR (MFMA A/B)
typedef __attribute__((ext_vector_type(4))) float v4f;   // MFMA C/D

// ---------------------------------------------------------------------------
// ws layout (ushort indices unless noted):
//   pack1 [0, 22528)        conv1 A-frags (weights), dense K: [ks 11][nt 4][lane 64][8]
//   pack2 [22528, 26624)    conv2 A-frags hi/lo nt-paired: [part 2][p 2][mt2 2][lane 64][8]
//   pack3 [26624, 47104)    conv3 B-frags (hi only): [ks 40][lane 64][8]
//   floats at us 47104 (float idx 23552):
#define B1F_F   23552      // 64
#define B2F_F   23616      // 32
#define B3F_F   23648      // 4
#define FLAG_I  23684      // int (1 = bf16 inputs/outputs, 0 = fp32)
#define PK1_US  0
#define PK2_US  22528
#define PK3_US  26624
#define H2_US   4242560    // bf16 NHWC [16][256][256][32] (32M us = 64 MB)
#define CVT_TOTAL (47104 + 100)
#define CVT_BLOCKS 185
// ---------------------------------------------------------------------------

__device__ __forceinline__ ushort_t f2us(float v) {
  __hip_bfloat16 h = __float2bfloat16(v);
  return *reinterpret_cast<ushort_t*>(&h);
}
__device__ __forceinline__ float us2f(unsigned int u) { return __uint_as_float(u << 16); }

// RNE-pack two finite floats into two bf16 (lo = a, hi = b).
__device__ __forceinline__ unsigned int bfpair(float a, float b) {
  unsigned int ua = __float_as_uint(a), ub = __float_as_uint(b);
  ua += 0x7fffu + ((ua >> 16) & 1u);
  ub += 0x7fffu + ((ub >> 16) & 1u);
  return (ua >> 16) | (ub & 0xffff0000u);
}

__device__ __forceinline__ float load_in(const void* p, int i, int isbf16) {
  if (isbf16) return us2f(((const unsigned short*)p)[i]);
  return ((const float*)p)[i];
}
__device__ __forceinline__ float4 load_in4(const void* p, int i4, int isbf16) {
  if (isbf16) {
    unsigned long long q = *(const unsigned long long*)((const unsigned short*)p + i4);
    return make_float4(us2f((unsigned int)(q & 0xffff)),
                       us2f((unsigned int)((q >> 16) & 0xffff)),
                       us2f((unsigned int)((q >> 32) & 0xffff)),
                       us2f((unsigned int)((q >> 48) & 0xffff)));
  }
  return *(const float4*)((const float*)p + i4);
}

__device__ __forceinline__ float cubicw(float d) {
  const float Ac = -0.75f;
  d = fabsf(d);
  float d2 = d * d, d3 = d2 * d;
  if (d <= 1.f) return (Ac + 2.f) * d3 - (Ac + 3.f) * d2 + 1.f;
  if (d < 2.f)  return Ac * d3 - 5.f * Ac * d2 + 8.f * Ac * d - 4.f * Ac;
  return 0.f;
}

// Per-block inline dtype probe (no cross-block dependency).
__device__ __forceinline__ int probe_dtype(const void* x) {
  __shared__ int scnt;
  const int tid = threadIdx.x;
  if (tid == 0) scnt = 0;
  __syncthreads();
  const unsigned short* xr = (const unsigned short*)x;
  int c = 0;
  for (int s = tid; s < 512; s += 256) {
    unsigned short h = xr[2 * s];
    int e = (h >> 7) & 0xFF;
    if (e >= 110 && e <= 135) c++;
  }
  if (c) atomicAdd(&scnt, c);
  __syncthreads();
  return (scnt >= 256) ? 1 : 0;
}

// ---------------- K_pre: dtype probe + build weight packs ------------------
__global__ __launch_bounds__(256) void k_pre(
    const void* __restrict__ x,
    const void* __restrict__ w1, const void* __restrict__ b1,
    const void* __restrict__ w2, const void* __restrict__ b2,
    const void* __restrict__ w3, const void* __restrict__ b3,
    ushort_t* __restrict__ wsus, float* __restrict__ wsf,
    int* __restrict__ flag) {
  const int f = probe_dtype(x);
  const int tid = threadIdx.x;
  if (blockIdx.x == 0 && tid == 0) flag[0] = f;

  int i = blockIdx.x * 256 + tid;
  if (i >= CVT_TOTAL) return;
  if (i < 22528) {
    // pack1 dense: k = ks*32+quad*8+j; k<324: tap=k>>2 (ky=tap/9,kx=tap%9), ic=k&3
    int j  = i & 7;
    int l  = (i >> 3) & 63;
    int nt = (i >> 9) & 3;
    int ks = i >> 11;
    int k  = ks * 32 + ((l >> 4) & 3) * 8 + j;
    int oc = nt * 16 + (l & 15);
    float v = 0.f;
    if (k < 324) {
      int tap = k >> 2, ic = k & 3;
      int ky = tap / 9, kx = tap - ky * 9;
      v = load_in(w1, ((oc * 4 + ic) * 9 + ky) * 9 + kx, f);
    }
    wsus[PK1_US + i] = f2us(v);
    return;
  }
  if (i < 26624) {
    // pack2 nt-paired hi/lo: [part][p][mt2][lane][8]
    // oc1 = (2p + j>>2)*16 + quad*4 + (j&3); oc2 = mt2*16 + lc
    int t = i - 22528;
    int j    = t & 7;
    int l    = (t >> 3) & 63;
    int mt2  = (t >> 9) & 1;
    int p    = (t >> 10) & 1;
    int part = (t >> 11) & 1;
    int oc1 = (2 * p + (j >> 2)) * 16 + ((l >> 4) & 3) * 4 + (j & 3);
    int oc2 = mt2 * 16 + (l & 15);
    float w = load_in(w2, oc2 * 64 + oc1, f);
    float hi = us2f(f2us(w));
    wsus[PK2_US + t] = part ? f2us(w - hi) : f2us(w);
    return;
  }
  if (i < 47104) {
    // pack3 (hi only): [ks 40][lane][8]; k=ky*256+jj*32+ic; n=dx*4+oc
    int t = i - 26624;
    int j8 = t & 7;
    int l  = (t >> 3) & 63;
    int ks = t >> 9;
    int k  = ks * 32 + ((l >> 4) & 3) * 8 + j8;
    int n  = l & 15;
    int ky = k >> 8, jj = (k >> 5) & 7, ic = k & 31;
    int dx = n >> 2, oc = n & 3;
    int kx = jj - dx;
    float w = 0.f;
    if (kx >= 0 && kx <= 4)
      w = load_in(w3, ((oc * 32 + ic) * 5 + ky) * 5 + kx, f);
    wsus[PK3_US + t] = f2us(w);
    return;
  }
  int t = i - 47104;
  if (t < 64) { wsf[B1F_F + t] = load_in(b1, t, f); return; }
  if (t < 96) { wsf[B2F_F + (t - 64)] = load_in(b2, t - 64, f); return; }
  if (t < 100) { wsf[B3F_F + (t - 96)] = load_in(b3, t - 96, f); return; }
}

// ---------------- K2: fused bicubic-staging + conv1 MFMA + conv2 MFMA ------
// tile 32x16 px, grid (8,16,16), 256 thr = 4 waves; wave owns 8 mtiles
// (128 px x 64 oc) -> halves weight-LDS bytes per unit work vs r8.
// Staging computes the x8 bicubic upscale inline (no `up` round-trip).
__global__ __launch_bounds__(256, 2) void k_conv12(
    const void* __restrict__ x, const ushort_t* __restrict__ wsus,
    const float* __restrict__ wsf, ushort_t* __restrict__ h2,
    const int* __restrict__ flag) {
  __shared__ __align__(16) ushort_t patchA[24 * 48 * 4];  // [y][x][4ic] 9216 B
  __shared__ __align__(16) ushort_t pack1L[22528];        // 45056 B
  __shared__ float wtab[32];                              // 8 phases x 4 taps
  const int f = flag[0];
  const int b  = blockIdx.z;
  const int x0 = blockIdx.x * 32, y0 = blockIdx.y * 16;
  const int tid = threadIdx.x;

  // phase-weight LUT (tx for phase p; matches verified k_upscale math)
  if (tid < 32) {
    int p = tid >> 2, a = tid & 3;
    float t = (p + 0.5f) * 0.125f + ((p >= 4) ? -0.5f : 0.5f);
    wtab[tid] = cubicw(t - (float)(a - 1));
  }
  // stage pack1 -> LDS (2816 x 16B)
  {
    const v8s* src = (const v8s*)(wsus + PK1_US);
    v8s* dst = (v8s*)pack1L;
#pragma unroll
    for (int i = 0; i < 11; ++i) dst[tid + i * 256] = src[tid + i * 256];
  }
  __syncthreads();   // wtab ready

  // stage 24x48 bicubic-upscaled patch (zero-pad OOB)
  for (int e = tid; e < 1152; e += 256) {
    int yy = e / 48, xx = e - yy * 48;
    int gy = y0 + yy - 4, gx = x0 + xx - 4;
    unsigned long long q = 0ull;
    if (gy >= 0 && gy < 256 && gx >= 0 && gx < 256) {
      int px = gx & 7, py = gy & 7;
      float4 wx = *(const float4*)(wtab + px * 4);
      float4 wy = *(const float4*)(wtab + py * 4);
      int bx = (gx >> 3) + ((px >= 4) ? 0 : -1);
      int by = (gy >> 3) + ((py >= 4) ? 0 : -1);
      int ix0 = min(max(bx - 1, 0), 31), ix1 = min(max(bx, 0), 31);
      int ix2 = min(max(bx + 1, 0), 31), ix3 = min(max(bx + 2, 0), 31);
      float ax = 0.f, ay = 0.f, az = 0.f, aw = 0.f;
      float wya[4] = {wy.x, wy.y, wy.z, wy.w};
#pragma unroll
      for (int a = 0; a < 4; a++) {
        int iy = min(max(by + a - 1, 0), 31);
        int rowb = (b * 32 + iy) * 32;
        float4 p0 = load_in4(x, (rowb + ix0) * 4, f);
        float4 p1 = load_in4(x, (rowb + ix1) * 4, f);
        float4 p2 = load_in4(x, (rowb + ix2) * 4, f);
        float4 p3 = load_in4(x, (rowb + ix3) * 4, f);
        float rx = wx.x * p0.x + wx.y * p1.x + wx.z * p2.x + wx.w * p3.x;
        float ry = wx.x * p0.y + wx.y * p1.y + wx.z * p2.y + wx.w * p3.y;
        float rz = wx.x * p0.z + wx.y * p1.z + wx.z * p2.z + wx.w * p3.z;
        float rw = wx.x * p0.w + wx.y * p1.w + wx.z * p2.w + wx.w * p3.w;
        ax = fmaf(wya[a], rx, ax); ay = fmaf(wya[a], ry, ay);
        az = fmaf(wya[a], rz, az); aw = fmaf(wya[a], rw, aw);
      }
      q = (unsigned long long)bfpair(ax, ay) |
          ((unsigned long long)bfpair(az, aw) << 32);
    }
    *(unsigned long long*)(patchA + e * 4) = q;
  }

  const int lane = tid & 63, wave = tid >> 6;
  const int quad = lane >> 4, lc = lane & 15;

  // hoist per-lane tap offsets (quad-dependent) out of the K-loop
  int off0_v[11], off1_v[11];
#pragma unroll
  for (int ks = 0; ks < 11; ++ks) {
    int tap0 = min(ks * 8 + quad * 2, 80);
    int tap1 = min(ks * 8 + quad * 2 + 1, 80);
    int ky0 = tap0 / 9, kx0 = tap0 - ky0 * 9;
    int ky1 = tap1 / 9, kx1 = tap1 - ky1 * 9;
    off0_v[ks] = (ky0 * 48 + kx0) << 2;
    off1_v[ks] = (ky1 * 48 + kx1) << 2;
  }
  int base_m[8];
#pragma unroll
  for (int i = 0; i < 8; ++i) {
    int py = wave * 4 + (i >> 1), pxh = (i & 1) << 4;
    base_m[i] = (py * 48 + pxh + lc) << 2;
  }

  // bias-init accumulators (D rows = oc = nt*16 + quad*4 + r)
  float4 b1q[4];
#pragma unroll
  for (int nt = 0; nt < 4; ++nt)
    b1q[nt] = *(const float4*)(wsf + B1F_F + nt * 16 + quad * 4);
  v4f acc[8][4];
#pragma unroll
  for (int i = 0; i < 8; ++i)
#pragma unroll
    for (int nt = 0; nt < 4; ++nt)
      acc[i][nt] = (v4f){b1q[nt].x, b1q[nt].y, b1q[nt].z, b1q[nt].w};

  __syncthreads();

  const v8s* __restrict__ Ap1 = (const v8s*)pack1L;
#pragma unroll
  for (int ks = 0; ks < 11; ++ks) {
    v8s Af[4];
#pragma unroll
    for (int nt = 0; nt < 4; ++nt) Af[nt] = Ap1[(ks * 4 + nt) * 64 + lane];
#pragma unroll
    for (int i = 0; i < 8; ++i) {
      union { unsigned long long q[2]; v8s v; } u;
      u.q[0] = *(const unsigned long long*)(patchA + base_m[i] + off0_v[ks]);
      u.q[1] = *(const unsigned long long*)(patchA + base_m[i] + off1_v[ks]);
#pragma unroll
      for (int nt = 0; nt < 4; ++nt)
        acc[i][nt] = __builtin_amdgcn_mfma_f32_16x16x32_bf16(Af[nt], u.v, acc[i][nt], 0, 0, 0);
    }
  }

  // epilogue: ReLU/pack -> conv2 MFMA (nt-paired hi/lo) -> ReLU, h2 store
  v8s w2f[2][2][2];  // [part][p][mt2]
#pragma unroll
  for (int part = 0; part < 2; ++part)
#pragma unroll
    for (int p = 0; p < 2; ++p)
#pragma unroll
      for (int mt2 = 0; mt2 < 2; ++mt2)
        w2f[part][p][mt2] =
            ((const v8s*)(wsus + PK2_US))[(((part * 2 + p) * 2 + mt2)) * 64 + lane];
  float4 b2q[2];
#pragma unroll
  for (int mt2 = 0; mt2 < 2; ++mt2)
    b2q[mt2] = *(const float4*)(wsf + B2F_F + mt2 * 16 + quad * 4);

#pragma unroll
  for (int i = 0; i < 8; ++i) {
    unsigned int pk[4][2];
#pragma unroll
    for (int nt = 0; nt < 4; ++nt) {
      float r0 = fmaxf(acc[i][nt][0], 0.f);
      float r1 = fmaxf(acc[i][nt][1], 0.f);
      float r2 = fmaxf(acc[i][nt][2], 0.f);
      float r3 = fmaxf(acc[i][nt][3], 0.f);
      pk[nt][0] = bfpair(r0, r1);
      pk[nt][1] = bfpair(r2, r3);
    }
    v4f a2[2];
#pragma unroll
    for (int mt2 = 0; mt2 < 2; ++mt2)
      a2[mt2] = (v4f){b2q[mt2].x, b2q[mt2].y, b2q[mt2].z, b2q[mt2].w};
#pragma unroll
    for (int p = 0; p < 2; ++p) {
      union { unsigned int q[4]; v8s v; } bu;
      bu.q[0] = pk[2 * p][0]; bu.q[1] = pk[2 * p][1];
      bu.q[2] = pk[2 * p + 1][0]; bu.q[3] = pk[2 * p + 1][1];
#pragma unroll
      for (int part = 0; part < 2; ++part)
#pragma unroll
        for (int mt2 = 0; mt2 < 2; ++mt2)
          a2[mt2] = __builtin_amdgcn_mfma_f32_16x16x32_bf16(
              w2f[part][p][mt2], bu.v, a2[mt2], 0, 0, 0);
    }
    int gy = y0 + wave * 4 + (i >> 1);
    int gx = x0 + ((i & 1) << 4) + lc;
    ushort_t* dst = h2 + (((b * 256 + gy) * 256 + gx) << 5) + (quad << 2);
#pragma unroll
    for (int mt2 = 0; mt2 < 2; ++mt2) {
      float v0 = fmaxf(a2[mt2][0], 0.f);
      float v1 = fmaxf(a2[mt2][1], 0.f);
      float v2 = fmaxf(a2[mt2][2], 0.f);
      float v3 = fmaxf(a2[mt2][3], 0.f);
      unsigned long long q =
          (unsigned long long)bfpair(v0, v1) |
          ((unsigned long long)bfpair(v2, v3) << 32);
      *(unsigned long long*)(dst + mt2 * 16) = q;
    }
  }
}

// ---------------- K3: MFMA conv5x5(32->4) via dx-in-N trick ----------------
// Weights (40 B-frags = 160 VGPR) preloaded to registers before the K-loop.
__global__ __launch_bounds__(256, 2) void k_conv3(
    const ushort_t* __restrict__ h2, const ushort_t* __restrict__ wsus,
    const float* __restrict__ wsf, void* __restrict__ out,
    const int* __restrict__ flag) {
  __shared__ __align__(16) ushort_t patch[20 * 1160];  // [y 20][x 36][ic 32] + 8 pad/row
  const int b  = blockIdx.z;
  const int x0 = blockIdx.x * 32, y0 = blockIdx.y * 16;
  const int tid = threadIdx.x;

  for (int e = tid; e < 720; e += 256) {
    int yy = e / 36, xx = e - yy * 36;
    int gy = y0 + yy - 2, gx = x0 + xx - 2;
    ushort_t* dst = patch + yy * 1160 + xx * 32;
    if (gy >= 0 && gy < 256 && gx >= 0 && gx < 256) {
      const ushort_t* src = h2 + (((b * 256 + gy) * 256 + gx) << 5);
#pragma unroll
      for (int c = 0; c < 4; ++c)
        *(float4*)(dst + c * 8) = *(const float4*)(src + c * 8);
    } else {
      float4 z = make_float4(0.f, 0.f, 0.f, 0.f);
#pragma unroll
      for (int c = 0; c < 4; ++c) *(float4*)(dst + c * 8) = z;
    }
  }

  const int lane = tid & 63, wave = tid >> 6;
  const int quad = lane >> 4, lc = lane & 15;

  v8s Wf[40];
  {
    const v8s* __restrict__ Bp3 = (const v8s*)(wsus + PK3_US);
#pragma unroll
    for (int ks = 0; ks < 40; ++ks) Wf[ks] = Bp3[ks * 64 + lane];
  }
  float b3v = (wsf + B3F_F)[lc & 3];
  __syncthreads();

  v4f acc[2];
  acc[0] = (v4f){b3v, b3v, b3v, b3v};
  acc[1] = (v4f){b3v, b3v, b3v, b3v};

#pragma unroll
  for (int ks = 0; ks < 40; ++ks) {
    int ky = ks >> 3, j = ks & 7;
    int rowoff = (lc + ky) * 1160 + j * 32 + quad * 8;
#pragma unroll
    for (int i = 0; i < 2; ++i) {
      int q = wave * 2 + i;
      v8s Af = *(const v8s*)(patch + rowoff + q * 128);
      acc[i] = __builtin_amdgcn_mfma_f32_16x16x32_bf16(Af, Wf[ks], acc[i], 0, 0, 0);
    }
  }

  const int fl = flag[0];
#pragma unroll
  for (int i = 0; i < 2; ++i) {
    int q = wave * 2 + i;
#pragma unroll
    for (int r = 0; r < 4; ++r) {
      int gy = y0 + (quad << 2) + r;
      int gx = x0 + (q << 2) + (lc >> 2);
      int idx = (((b * 256 + gy) * 256 + gx) << 2) + (lc & 3);
      float vv = acc[i][r];
      if (fl) ((ushort_t*)out)[idx] = f2us(vv);
      else    ((float*)out)[idx] = vv;
    }
  }
}

// ---------------------------------------------------------------------------
extern "C" void kernel_launch(void* const* d_in, const int* in_sizes, int n_in,
                              void* d_out, int out_size, void* d_ws, size_t ws_size,
                              hipStream_t stream) {
  const void* x  = d_in[0];
  const void* w1 = d_in[1];
  const void* b1 = d_in[2];
  const void* w2 = d_in[3];
  const void* b2 = d_in[4];
  const void* w3 = d_in[5];
  const void* b3 = d_in[6];

  ushort_t* wsus = (ushort_t*)d_ws;
  float* wsf = (float*)d_ws;
  int* flag = (int*)((float*)d_ws + FLAG_I);
  ushort_t* h2 = wsus + H2_US;

  k_pre<<<CVT_BLOCKS, 256, 0, stream>>>(x, w1, b1, w2, b2, w3, b3, wsus, wsf, flag);
  k_conv12<<<dim3(8, 16, 16), 256, 0, stream>>>(x, wsus, wsf, h2, flag);
  k_conv3<<<dim3(8, 16, 16), 256, 0, stream>>>(h2, wsus, wsf, d_out, flag);
}